// Round 13
// baseline (165.269 us; speedup 1.0000x reference)
//
#include <hip/hip_runtime.h>
#include <hip/hip_bf16.h>

#define NV 40962
#define NK 9
#define CIN 32
#define COUT 32
#define NT 2561                // v-tiles of 16
#define NB2 1281               // conv blocks: each wave does 2 tiles
#define NV81 (NV * 81)
#define NV9  (NV * 9)

typedef __attribute__((ext_vector_type(8))) short bf16x8;
typedef __attribute__((ext_vector_type(4))) float f32x4;
typedef __attribute__((ext_vector_type(2))) float f32x2;

// ---- packed f32 FMA/MUL, src0 broadcast from pair half (VOP3P op_sel)
#define PKFMA_L(A, G, R) asm("v_pk_fma_f32 %0, %1, %2, %0 op_sel:[0,0,0] op_sel_hi:[0,1,1]" : "+v"(A) : "v"(G), "v"(R))
#define PKFMA_H(A, G, R) asm("v_pk_fma_f32 %0, %1, %2, %0 op_sel:[1,0,0] op_sel_hi:[1,1,1]" : "+v"(A) : "v"(G), "v"(R))
#define PKMUL_L(A, G, R) asm("v_pk_mul_f32 %0, %1, %2 op_sel:[0,0] op_sel_hi:[0,1]" : "=v"(A) : "v"(G), "v"(R))
#define PKMUL_H(A, G, R) asm("v_pk_mul_f32 %0, %1, %2 op_sel:[1,0] op_sel_hi:[1,1]" : "=v"(A) : "v"(G), "v"(R))

#define ACC(cc, j) ((j) == 8 ? acc8[cc] : (((j) & 1) ? acc2[cc][(j) >> 1].y \
                                                     : acc2[cc][(j) >> 1].x))

// f32 pair -> packed bf16 dword (a=low), via v_cvt_pk_bf16_f32 (RNE)
__device__ __forceinline__ unsigned pkbf(float a, float b) {
    union { __hip_bfloat162 h2; unsigned u; } cv;
    cv.h2 = __float22bfloat162_rn(make_float2(a, b));
    return cv.u;
}

// ---------------------------------------------------------------------------
// Kernel 1: transpose + weight-convert fused (VERBATIM R4 — proven).
// x [128 rows=(b*32+c)][V] f32 -> xt [v][coct(4)][b(4)][8ch] bf16.
// Blocks 0..35 also do the conv-weight f32->bf16 K-permute.
// ---------------------------------------------------------------------------
__global__ void __launch_bounds__(256) transpose_x_bf16(
    const float* __restrict__ x, unsigned* __restrict__ xtw,
    const float* __restrict__ w, unsigned short* __restrict__ wbf)
{
    __shared__ unsigned U[64 * 65];          // [v][64 dw + 1 pad], 16640 B
    const int t = threadIdx.x;

    // merged convert_w: wbf[o][k' = j*32 + c]
    const int ci = blockIdx.x * 256 + t;
    if (ci < COUT * CIN * NK) {
        const int o = ci / 288;
        const int r = ci - o * 288;
        const int c = r / 9;
        const int j = r - c * 9;
        unsigned u = __float_as_uint(w[ci]);
        wbf[o * 288 + j * 32 + c] =
            (unsigned short)((u + 0x7FFFu + ((u >> 16) & 1u)) >> 16);
    }

    const int v0  = blockIdx.x * 64;
    const int l16 = t & 15;
    const int p   = t >> 4;                  // row-pair group 0..15

    #pragma unroll
    for (int i = 0; i < 4; ++i) {
        const int q    = p * 4 + i;          // row-pair 0..63
        const int r0   = 2 * q;              // even row; r0+1 same batch
        const int bb   = r0 >> 5;
        const int c0   = r0 & 31;            // even channel
        const int dwb  = (c0 >> 3) * 16 + bb * 4 + ((c0 & 7) >> 1);
        const float* rowA = x + (size_t)r0 * NV + v0;
        const float* rowB = rowA + NV;
        #pragma unroll
        for (int hv = 0; hv < 2; ++hv) {
            const int v = l16 * 2 + hv * 32; // even, pair (v, v+1)
            float2 a = make_float2(0.f, 0.f), c2 = make_float2(0.f, 0.f);
            if (v0 + v < NV) {               // NV even: pair never crosses
                a  = *(const float2*)(rowA + v);
                c2 = *(const float2*)(rowB + v);
            }
            U[(v    ) * 65 + dwb] = pkbf(a.x, c2.x);
            U[(v + 1) * 65 + dwb] = pkbf(a.y, c2.y);
        }
    }
    __syncthreads();

    // write out: full 64B sectors (lanes qo=0..3 cover one sector)
    const int v  = t >> 2;
    const int qo = t & 3;
    if (v0 + v < NV) {
        #pragma unroll
        for (int j = 0; j < 4; ++j) {
            const int n = j * 4 + qo;        // 16B chunk id 0..15
            uint4 d;
            d.x = U[v * 65 + n * 4 + 0];
            d.y = U[v * 65 + n * 4 + 1];
            d.z = U[v * 65 + n * 4 + 2];
            d.w = U[v * 65 + n * 4 + 3];
            *(uint4*)&xtw[(size_t)(v0 + v) * 64 + n * 4] = d;
        }
    }
}

// ---------------------------------------------------------------------------
// Kernel 2: R4 conv body, 2 TILES PER WAVE (wave-count A/B test).
// Across R0/R4/R11/R12 conv time is pinned at ~45us whenever total waves
// = 10244, independent of structure (incl. R11: blocks halved, waves
// constant -> time constant). Hypothesis: global wave launch/retire rate
// (~4.4ns/wave) is the floor. This kernel HALVES wave count: grid 1281,
// each wave runs tile t0=blockIdx*2 then t1=t0+1 with R4's exact per-tile
// body. Weights/bias load once per wave (2x amortized). Both tiles'
// idx+itp staged up front (one wave_barrier); tile B's gathers reuse
// tile A's dead g[] registers, issued before MFMA A + stores A.
// NO __syncthreads; waves fully autonomous.
// Lane: coct = l>>4 (k-octet), b = (l>>2)&3, vv = l&3, arow = l&15.
// ---------------------------------------------------------------------------
__global__ void __launch_bounds__(256, 2) sparse_conv_mfma(
    const unsigned short* __restrict__ xt, const int* __restrict__ index,
    const float* __restrict__ itp, const unsigned short* __restrict__ wbf,
    const float* __restrict__ bias, float* __restrict__ out)
{
    __shared__ float itp_s[4][2][4 * 108];   // per-wave 2 slices, 13824 B

    const int t    = threadIdx.x;
    const int w    = t >> 6;
    const int lane = t & 63;
    const int arow = lane & 15;
    const int coct = lane >> 4;
    const int b    = (lane >> 2) & 3;
    const int vv   = lane & 3;
    const int t0   = blockIdx.x * 2;
    const int t1   = t0 + 1;
    const bool vB  = (t1 < NT);

    const int lidx = (lane < 36) ? lane : 35;

    // 1. idx loads for both tiles
    int iaA = t0 * 144 + w * 36 + lidx;
    iaA = iaA < NV9 ? iaA : NV9 - 1;
    const int myidxA = index[iaA];
    int iaB = (vB ? t1 : t0) * 144 + w * 36 + lidx;
    iaB = iaB < NV9 ? iaB : NV9 - 1;
    const int myidxB = index[iaB];

    // 2. itp loads for both tiles (contiguous, 324 floats per wave-tile)
    float ivA[6], ivB[6];
    {
        const size_t baseA = (size_t)(t0 * 16 + w * 4) * 81;
        const size_t baseB = (size_t)((vB ? t1 : t0) * 16 + w * 4) * 81;
        #pragma unroll
        for (int i = 0; i < 6; ++i) {
            const int o = i * 64 + lane;
            ivA[i] = (o < 324 && baseA + o < (size_t)NV81) ? itp[baseA + o]
                                                           : 0.0f;
            ivB[i] = (o < 324 && baseB + o < (size_t)NV81) ? itp[baseB + o]
                                                           : 0.0f;
        }
    }

    // 3. weight loads -> regs (tile-invariant, amortized over both tiles)
    const unsigned short* wb0 = wbf + arow * 288 + coct * 8;
    uint4 wa0[NK], wa1[NK];
    #pragma unroll
    for (int ks = 0; ks < NK; ++ks) {
        wa0[ks] = *(const uint4*)(wb0 + ks * 32);
        wa1[ks] = *(const uint4*)(wb0 + 16 * 288 + ks * 32);
    }

    // bias -> regs
    float bs0[4], bs1[4];
    #pragma unroll
    for (int r = 0; r < 4; ++r) {
        bs0[r] = bias[coct * 4 + r];
        bs1[r] = bias[coct * 4 + 16 + r];
    }

    // 4. tile A gathers
    const unsigned short* gbase = xt + coct * 32 + b * 8;
    int nbr[NK];
    #pragma unroll
    for (int n = 0; n < NK; ++n) nbr[n] = __shfl(myidxA, vv * 9 + n);
    uint4 g[NK];
    #pragma unroll
    for (int n = 0; n < NK; ++n)
        g[n] = *(const uint4*)(gbase + (size_t)nbr[n] * 128);

    // 5. scatter BOTH tiles' itp into this wave's LDS slices (frees ivB)
    #pragma unroll
    for (int i = 0; i < 6; ++i) {
        const int o = i * 64 + lane;
        if (o < 324) {
            const int vloc = o / 81;
            const int r2   = o - vloc * 81;
            const int kk   = r2 / 9;
            const int jj   = r2 - kk * 9;
            itp_s[w][0][vloc * 108 + kk * 12 + jj] = ivA[i];
            itp_s[w][1][vloc * 108 + kk * 12 + jj] = ivB[i];
        }
    }
    __builtin_amdgcn_wave_barrier();         // pin write->read order

    f32x4 c0, c1;
    unsigned frag[9][4];

    #pragma unroll
    for (int tt = 0; tt < 2; ++tt) {
        if (tt == 1 && !vB) break;

        // interp + frag pack (VERBATIM R4 body)
        unsigned nzbits = 0;
        #pragma unroll
        for (int n = 0; n < NK; ++n)
            nzbits |= (g[n].x | g[n].y | g[n].z | g[n].w);
        nzbits &= 0x7FFF7FFFu;

        const float* ib = &itp_s[w][tt][vv * 108];
        #pragma unroll
        for (int h = 0; h < 2; ++h) {        // 4 channels per half
            f32x2 acc2[4][4];
            float acc8[4];
            #pragma unroll
            for (int n = 0; n < NK; ++n) {
                const uint2 gk = h ? make_uint2(g[n].z, g[n].w)
                                   : make_uint2(g[n].x, g[n].y);
                f32x2 gp01, gp23;
                gp01.x = __uint_as_float(gk.x << 16);
                gp01.y = __uint_as_float(gk.x & 0xFFFF0000u);
                gp23.x = __uint_as_float(gk.y << 16);
                gp23.y = __uint_as_float(gk.y & 0xFFFF0000u);
                const float* ir = ib + n * 12;
                const f32x4 ra = *(const f32x4*)ir;
                const f32x4 rb = *(const f32x4*)(ir + 4);
                const float r8 = ir[8];
                f32x2 rp[4];
                rp[0] = __builtin_shufflevector(ra, ra, 0, 1);
                rp[1] = __builtin_shufflevector(ra, ra, 2, 3);
                rp[2] = __builtin_shufflevector(rb, rb, 0, 1);
                rp[3] = __builtin_shufflevector(rb, rb, 2, 3);
                if (n == 0) {
                    #pragma unroll
                    for (int jp = 0; jp < 4; ++jp) {
                        PKMUL_L(acc2[0][jp], gp01, rp[jp]);
                        PKMUL_H(acc2[1][jp], gp01, rp[jp]);
                        PKMUL_L(acc2[2][jp], gp23, rp[jp]);
                        PKMUL_H(acc2[3][jp], gp23, rp[jp]);
                    }
                    acc8[0] = gp01.x * r8; acc8[1] = gp01.y * r8;
                    acc8[2] = gp23.x * r8; acc8[3] = gp23.y * r8;
                } else {
                    #pragma unroll
                    for (int jp = 0; jp < 4; ++jp) {
                        PKFMA_L(acc2[0][jp], gp01, rp[jp]);
                        PKFMA_H(acc2[1][jp], gp01, rp[jp]);
                        PKFMA_L(acc2[2][jp], gp23, rp[jp]);
                        PKFMA_H(acc2[3][jp], gp23, rp[jp]);
                    }
                    acc8[0] += gp01.x * r8; acc8[1] += gp01.y * r8;
                    acc8[2] += gp23.x * r8; acc8[3] += gp23.y * r8;
                }
            }
            #pragma unroll
            for (int ks = 0; ks < 9; ++ks) {
                frag[ks][2 * h]     = pkbf(ACC(0, ks), ACC(1, ks));
                frag[ks][2 * h + 1] = pkbf(ACC(2, ks), ACC(3, ks));
            }
        }

        // issue tile B's gathers NOW (g dead; hides under MFMA A + stores)
        if (tt == 0 && vB) {
            #pragma unroll
            for (int n = 0; n < NK; ++n) nbr[n] = __shfl(myidxB, vv * 9 + n);
            #pragma unroll
            for (int n = 0; n < NK; ++n)
                g[n] = *(const uint4*)(gbase + (size_t)nbr[n] * 128);
        }

        // nz over all 32 channels of this lane's (b, vv) column
        unsigned nzw = nzbits;
        nzw |= __shfl_xor(nzw, 16);
        nzw |= __shfl_xor(nzw, 32);

        // MFMA: 9 K'-steps x 2 o-halves; A-operand straight from registers
        c0 = (f32x4){0.f, 0.f, 0.f, 0.f};
        c1 = (f32x4){0.f, 0.f, 0.f, 0.f};
        #pragma unroll
        for (int ks = 0; ks < 9; ++ks) {
            union { uint4 u; bf16x8 v; } bfr, au0, au1;
            bfr.u.x = frag[ks][0]; bfr.u.y = frag[ks][1];
            bfr.u.z = frag[ks][2]; bfr.u.w = frag[ks][3];
            au0.u = wa0[ks];
            au1.u = wa1[ks];
            c0 = __builtin_amdgcn_mfma_f32_16x16x32_bf16(au0.v, bfr.v, c0, 0, 0, 0);
            c1 = __builtin_amdgcn_mfma_f32_16x16x32_bf16(au1.v, bfr.v, c1, 0, 0, 0);
        }

        // epilogue: C col = arow = b*4+vv, row o = coct*4+r (+16)
        const int vglob = (t0 + tt) * 16 + w * 4 + vv;
        if (vglob < NV) {
            const float m = nzw ? 1.0f : 0.0f;
            float* ob = out + (size_t)b * (COUT * NV) + vglob;
            #pragma unroll
            for (int r = 0; r < 4; ++r) {
                ob[(size_t)(coct * 4 + r) * NV]      = (c0[r] + bs0[r]) * m;
                ob[(size_t)(coct * 4 + 16 + r) * NV] = (c1[r] + bs1[r]) * m;
            }
        }
    }
}

// ---------------------------------------------------------------------------
extern "C" void kernel_launch(void* const* d_in, const int* in_sizes, int n_in,
                              void* d_out, int out_size, void* d_ws, size_t ws_size,
                              hipStream_t stream)
{
    const float* x     = (const float*)d_in[0];
    const int*   index = (const int*)  d_in[1];
    const float* itp   = (const float*)d_in[2];
    const float* w     = (const float*)d_in[3];
    const float* bias  = (const float*)d_in[4];
    float*       out   = (float*)d_out;

    unsigned short* xt  = (unsigned short*)d_ws;                 // 10.5 MB
    unsigned short* wbf = (unsigned short*)((char*)d_ws + (size_t)NV * 256);

    const int vchunks = (NV + 63) / 64;      // 641 (>= 36 convert blocks)
    hipLaunchKernelGGL(transpose_x_bf16, dim3(vchunks), dim3(256), 0,
                       stream, x, (unsigned*)xt, w, wbf);
    hipLaunchKernelGGL(sparse_conv_mfma, dim3(NB2), dim3(256), 0,
                       stream, xt, index, itp, wbf, bias, out);
}

// Round 14
// 117.602 us; speedup vs baseline: 1.4053x; 1.4053x over previous
//
#include <hip/hip_runtime.h>
#include <hip/hip_bf16.h>

#define NV 40962
#define NK 9
#define CIN 32
#define COUT 32
#define NT 2561                // v-tiles of 16
#define NB2 1281               // conv blocks: each wave does 2 tiles
#define NV81 (NV * 81)
#define NV9  (NV * 9)

typedef __attribute__((ext_vector_type(8))) short bf16x8;
typedef __attribute__((ext_vector_type(4))) float f32x4;
typedef __attribute__((ext_vector_type(2))) float f32x2;

// ---- packed f32 FMA/MUL, src0 broadcast from pair half (VOP3P op_sel)
#define PKFMA_L(A, G, R) asm("v_pk_fma_f32 %0, %1, %2, %0 op_sel:[0,0,0] op_sel_hi:[0,1,1]" : "+v"(A) : "v"(G), "v"(R))
#define PKFMA_H(A, G, R) asm("v_pk_fma_f32 %0, %1, %2, %0 op_sel:[1,0,0] op_sel_hi:[1,1,1]" : "+v"(A) : "v"(G), "v"(R))
#define PKMUL_L(A, G, R) asm("v_pk_mul_f32 %0, %1, %2 op_sel:[0,0] op_sel_hi:[0,1]" : "=v"(A) : "v"(G), "v"(R))
#define PKMUL_H(A, G, R) asm("v_pk_mul_f32 %0, %1, %2 op_sel:[1,0] op_sel_hi:[1,1]" : "=v"(A) : "v"(G), "v"(R))

#define ACC(cc, j) ((j) == 8 ? acc8[cc] : (((j) & 1) ? acc2[cc][(j) >> 1].y \
                                                     : acc2[cc][(j) >> 1].x))

// f32 pair -> packed bf16 dword (a=low), via v_cvt_pk_bf16_f32 (RNE)
__device__ __forceinline__ unsigned pkbf(float a, float b) {
    union { __hip_bfloat162 h2; unsigned u; } cv;
    cv.h2 = __float22bfloat162_rn(make_float2(a, b));
    return cv.u;
}

// ---------------------------------------------------------------------------
// Kernel 1: transpose + weight-convert fused (VERBATIM R4 — proven).
// x [128 rows=(b*32+c)][V] f32 -> xt [v][coct(4)][b(4)][8ch] bf16.
// Blocks 0..35 also do the conv-weight f32->bf16 K-permute.
// ---------------------------------------------------------------------------
__global__ void __launch_bounds__(256) transpose_x_bf16(
    const float* __restrict__ x, unsigned* __restrict__ xtw,
    const float* __restrict__ w, unsigned short* __restrict__ wbf)
{
    __shared__ unsigned U[64 * 65];          // [v][64 dw + 1 pad], 16640 B
    const int t = threadIdx.x;

    // merged convert_w: wbf[o][k' = j*32 + c]
    const int ci = blockIdx.x * 256 + t;
    if (ci < COUT * CIN * NK) {
        const int o = ci / 288;
        const int r = ci - o * 288;
        const int c = r / 9;
        const int j = r - c * 9;
        unsigned u = __float_as_uint(w[ci]);
        wbf[o * 288 + j * 32 + c] =
            (unsigned short)((u + 0x7FFFu + ((u >> 16) & 1u)) >> 16);
    }

    const int v0  = blockIdx.x * 64;
    const int l16 = t & 15;
    const int p   = t >> 4;                  // row-pair group 0..15

    #pragma unroll
    for (int i = 0; i < 4; ++i) {
        const int q    = p * 4 + i;          // row-pair 0..63
        const int r0   = 2 * q;              // even row; r0+1 same batch
        const int bb   = r0 >> 5;
        const int c0   = r0 & 31;            // even channel
        const int dwb  = (c0 >> 3) * 16 + bb * 4 + ((c0 & 7) >> 1);
        const float* rowA = x + (size_t)r0 * NV + v0;
        const float* rowB = rowA + NV;
        #pragma unroll
        for (int hv = 0; hv < 2; ++hv) {
            const int v = l16 * 2 + hv * 32; // even, pair (v, v+1)
            float2 a = make_float2(0.f, 0.f), c2 = make_float2(0.f, 0.f);
            if (v0 + v < NV) {               // NV even: pair never crosses
                a  = *(const float2*)(rowA + v);
                c2 = *(const float2*)(rowB + v);
            }
            U[(v    ) * 65 + dwb] = pkbf(a.x, c2.x);
            U[(v + 1) * 65 + dwb] = pkbf(a.y, c2.y);
        }
    }
    __syncthreads();

    // write out: full 64B sectors (lanes qo=0..3 cover one sector)
    const int v  = t >> 2;
    const int qo = t & 3;
    if (v0 + v < NV) {
        #pragma unroll
        for (int j = 0; j < 4; ++j) {
            const int n = j * 4 + qo;        // 16B chunk id 0..15
            uint4 d;
            d.x = U[v * 65 + n * 4 + 0];
            d.y = U[v * 65 + n * 4 + 1];
            d.z = U[v * 65 + n * 4 + 2];
            d.w = U[v * 65 + n * 4 + 3];
            *(uint4*)&xtw[(size_t)(v0 + v) * 64 + n * 4] = d;
        }
    }
}

// ---------------------------------------------------------------------------
// Kernel 2: 2 TILES PER WAVE, spill-proof (clean wave-count A/B test).
// R13's version spilled (needed ~137 arch VGPR > the 128 ceiling from the
// unified-file arch/acc split). Here the MFMA A-operand (weights) lives in
// LDS (Wlds, R0/R3 mapping — measured perf-neutral vs registers for
// 1-tile: R0 45.5us = R4 45.5us), freeing 72 VGPRs. Peak live ~110.
// Waves: 10244 -> 5124 (grid 1281). Pipeline per wave:
//   idxA+itpA+gathersA issue BEFORE the single Wlds __syncthreads
//   scatter itpA -> slot; RELOAD iv[] with itpB (consumed after MFMA A)
//   interp A (g dies) -> gathers B reuse g (hide under nz+MFMA A+stores A)
//   MFMA A (Wlds ds_read_b128) -> stores A
//   wave_barrier -> scatter itpB into SAME slot -> interp/MFMA/store B.
// No block coupling: each wave fully autonomous after the one barrier.
// Lane: coct = l>>4 (k-octet), b = (l>>2)&3, vv = l&3, arow = l&15.
// ---------------------------------------------------------------------------
__global__ void __launch_bounds__(256, 2) sparse_conv_mfma(
    const unsigned short* __restrict__ xt, const int* __restrict__ index,
    const float* __restrict__ itp, const unsigned short* __restrict__ wbf,
    const float* __restrict__ bias, float* __restrict__ out)
{
    __shared__ unsigned short Wlds[9 * 32 * 32];   // 18432 B, [j][o][c]
    __shared__ float itp_s[4][4 * 108];            //  6912 B, 1 slot/wave

    const int t    = threadIdx.x;
    const int w    = t >> 6;
    const int lane = t & 63;
    const int arow = lane & 15;
    const int coct = lane >> 4;
    const int b    = (lane >> 2) & 3;
    const int vv   = lane & 3;
    const int t0   = blockIdx.x * 2;
    const int t1   = t0 + 1;
    const bool vB  = (t1 < NT);
    const int lidx = (lane < 36) ? lane : 35;

    // stage Wlds: dst 16B-chunk n -> (j = n>>7, o = (n>>2)&31, cq = n&3)
    #pragma unroll
    for (int r = 0; r < 5; ++r) {
        const int n = t + r * 256;
        if (n < 1152) {
            const int j  = n >> 7;
            const int o  = (n >> 2) & 31;
            const int cq = n & 3;
            ((uint4*)Wlds)[n] = ((const uint4*)wbf)[o * 36 + j * 4 + cq];
        }
    }

    // bias -> regs
    float bs0[4], bs1[4];
    #pragma unroll
    for (int r = 0; r < 4; ++r) {
        bs0[r] = bias[coct * 4 + r];
        bs1[r] = bias[coct * 4 + 16 + r];
    }

    // tile A: idx + itp + gathers, issued before the barrier
    int iaA = t0 * 144 + w * 36 + lidx;
    iaA = iaA < NV9 ? iaA : NV9 - 1;
    const int myidxA = index[iaA];

    float iv[6];
    {
        const size_t baseA = (size_t)(t0 * 16 + w * 4) * 81;
        #pragma unroll
        for (int i = 0; i < 6; ++i) {
            const int o = i * 64 + lane;
            iv[i] = (o < 324 && baseA + o < (size_t)NV81) ? itp[baseA + o]
                                                          : 0.0f;
        }
    }

    const unsigned short* gbase = xt + coct * 32 + b * 8;
    int nbr[NK];
    #pragma unroll
    for (int n = 0; n < NK; ++n) nbr[n] = __shfl(myidxA, vv * 9 + n);
    uint4 g[NK];
    #pragma unroll
    for (int n = 0; n < NK; ++n)
        g[n] = *(const uint4*)(gbase + (size_t)nbr[n] * 128);

    // idx for tile B (1 reg, loaded far ahead of use)
    int iaB = (vB ? t1 : t0) * 144 + w * 36 + lidx;
    iaB = iaB < NV9 ? iaB : NV9 - 1;
    const int myidxB = index[iaB];

    __syncthreads();                         // Wlds ready (only barrier)

    // scatter itpA -> this wave's slot
    #pragma unroll
    for (int i = 0; i < 6; ++i) {
        const int o = i * 64 + lane;
        if (o < 324) {
            const int vloc = o / 81;
            const int r2   = o - vloc * 81;
            const int kk   = r2 / 9;
            const int jj   = r2 - kk * 9;
            itp_s[w][vloc * 108 + kk * 12 + jj] = iv[i];
        }
    }
    __builtin_amdgcn_wave_barrier();         // writes before interp-A reads

    // reload iv with tile B's itp (consumed only after MFMA A)
    {
        const size_t baseB = (size_t)((vB ? t1 : t0) * 16 + w * 4) * 81;
        #pragma unroll
        for (int i = 0; i < 6; ++i) {
            const int o = i * 64 + lane;
            iv[i] = (o < 324 && baseB + o < (size_t)NV81) ? itp[baseB + o]
                                                          : 0.0f;
        }
    }

    unsigned frag[9][4];
    const float* ib = &itp_s[w][vv * 108];

    #pragma unroll
    for (int tt = 0; tt < 2; ++tt) {
        if (tt == 1 && !vB) break;

        // nz fold from g (must precede g overwrite below)
        unsigned nzbits = 0;
        #pragma unroll
        for (int n = 0; n < NK; ++n)
            nzbits |= (g[n].x | g[n].y | g[n].z | g[n].w);
        nzbits &= 0x7FFF7FFFu;

        // interp + frag pack (VERBATIM R4 body; consumes g)
        #pragma unroll
        for (int h = 0; h < 2; ++h) {        // 4 channels per half
            f32x2 acc2[4][4];
            float acc8[4];
            #pragma unroll
            for (int n = 0; n < NK; ++n) {
                const uint2 gk = h ? make_uint2(g[n].z, g[n].w)
                                   : make_uint2(g[n].x, g[n].y);
                f32x2 gp01, gp23;
                gp01.x = __uint_as_float(gk.x << 16);
                gp01.y = __uint_as_float(gk.x & 0xFFFF0000u);
                gp23.x = __uint_as_float(gk.y << 16);
                gp23.y = __uint_as_float(gk.y & 0xFFFF0000u);
                const float* ir = ib + n * 12;
                const f32x4 ra = *(const f32x4*)ir;
                const f32x4 rb = *(const f32x4*)(ir + 4);
                const float r8 = ir[8];
                f32x2 rp[4];
                rp[0] = __builtin_shufflevector(ra, ra, 0, 1);
                rp[1] = __builtin_shufflevector(ra, ra, 2, 3);
                rp[2] = __builtin_shufflevector(rb, rb, 0, 1);
                rp[3] = __builtin_shufflevector(rb, rb, 2, 3);
                if (n == 0) {
                    #pragma unroll
                    for (int jp = 0; jp < 4; ++jp) {
                        PKMUL_L(acc2[0][jp], gp01, rp[jp]);
                        PKMUL_H(acc2[1][jp], gp01, rp[jp]);
                        PKMUL_L(acc2[2][jp], gp23, rp[jp]);
                        PKMUL_H(acc2[3][jp], gp23, rp[jp]);
                    }
                    acc8[0] = gp01.x * r8; acc8[1] = gp01.y * r8;
                    acc8[2] = gp23.x * r8; acc8[3] = gp23.y * r8;
                } else {
                    #pragma unroll
                    for (int jp = 0; jp < 4; ++jp) {
                        PKFMA_L(acc2[0][jp], gp01, rp[jp]);
                        PKFMA_H(acc2[1][jp], gp01, rp[jp]);
                        PKFMA_L(acc2[2][jp], gp23, rp[jp]);
                        PKFMA_H(acc2[3][jp], gp23, rp[jp]);
                    }
                    acc8[0] += gp01.x * r8; acc8[1] += gp01.y * r8;
                    acc8[2] += gp23.x * r8; acc8[3] += gp23.y * r8;
                }
            }
            #pragma unroll
            for (int ks = 0; ks < 9; ++ks) {
                frag[ks][2 * h]     = pkbf(ACC(0, ks), ACC(1, ks));
                frag[ks][2 * h + 1] = pkbf(ACC(2, ks), ACC(3, ks));
            }
        }

        // tile A only: issue tile B's gathers now (g dead; latency hides
        // under nz-reduce + MFMA A + stores A)
        if (tt == 0 && vB) {
            #pragma unroll
            for (int n = 0; n < NK; ++n) nbr[n] = __shfl(myidxB, vv * 9 + n);
            #pragma unroll
            for (int n = 0; n < NK; ++n)
                g[n] = *(const uint4*)(gbase + (size_t)nbr[n] * 128);
        }

        // nz over all 32 channels of this lane's (b, vv) column
        unsigned nzw = nzbits;
        nzw |= __shfl_xor(nzw, 16);
        nzw |= __shfl_xor(nzw, 32);

        // MFMA: 9 K'-steps x 2 o-halves; A from Wlds b128 reads
        f32x4 c0 = {0.f, 0.f, 0.f, 0.f};
        f32x4 c1 = {0.f, 0.f, 0.f, 0.f};
        #pragma unroll
        for (int ks = 0; ks < 9; ++ks) {
            union { uint4 u; bf16x8 v; } bfr;
            bfr.u.x = frag[ks][0]; bfr.u.y = frag[ks][1];
            bfr.u.z = frag[ks][2]; bfr.u.w = frag[ks][3];
            const bf16x8 wa0 =
                *(const bf16x8*)&Wlds[(ks * 32 + arow) * 32 + coct * 8];
            const bf16x8 wa1 =
                *(const bf16x8*)&Wlds[(ks * 32 + arow + 16) * 32 + coct * 8];
            c0 = __builtin_amdgcn_mfma_f32_16x16x32_bf16(wa0, bfr.v, c0, 0, 0, 0);
            c1 = __builtin_amdgcn_mfma_f32_16x16x32_bf16(wa1, bfr.v, c1, 0, 0, 0);
        }

        // epilogue: C col = arow = b*4+vv, row o = coct*4+r (+16)
        const int vglob = (t0 + tt) * 16 + w * 4 + vv;
        if (vglob < NV) {
            const float m = nzw ? 1.0f : 0.0f;
            float* ob = out + (size_t)b * (COUT * NV) + vglob;
            #pragma unroll
            for (int r = 0; r < 4; ++r) {
                ob[(size_t)(coct * 4 + r) * NV]      = (c0[r] + bs0[r]) * m;
                ob[(size_t)(coct * 4 + 16 + r) * NV] = (c1[r] + bs1[r]) * m;
            }
        }

        // prep tile B's itp slot (reuse same slot; A's LDS reads are done)
        if (tt == 0 && vB) {
            __builtin_amdgcn_wave_barrier();     // A reads before B writes
            #pragma unroll
            for (int i = 0; i < 6; ++i) {
                const int o = i * 64 + lane;
                if (o < 324) {
                    const int vloc = o / 81;
                    const int r2   = o - vloc * 81;
                    const int kk   = r2 / 9;
                    const int jj   = r2 - kk * 9;
                    itp_s[w][vloc * 108 + kk * 12 + jj] = iv[i];
                }
            }
            __builtin_amdgcn_wave_barrier();     // B writes before B reads
        }
    }
}

// ---------------------------------------------------------------------------
extern "C" void kernel_launch(void* const* d_in, const int* in_sizes, int n_in,
                              void* d_out, int out_size, void* d_ws, size_t ws_size,
                              hipStream_t stream)
{
    const float* x     = (const float*)d_in[0];
    const int*   index = (const int*)  d_in[1];
    const float* itp   = (const float*)d_in[2];
    const float* w     = (const float*)d_in[3];
    const float* bias  = (const float*)d_in[4];
    float*       out   = (float*)d_out;

    unsigned short* xt  = (unsigned short*)d_ws;                 // 10.5 MB
    unsigned short* wbf = (unsigned short*)((char*)d_ws + (size_t)NV * 256);

    const int vchunks = (NV + 63) / 64;      // 641 (>= 36 convert blocks)
    hipLaunchKernelGGL(transpose_x_bf16, dim3(vchunks), dim3(256), 0,
                       stream, x, (unsigned*)xt, w, wbf);
    hipLaunchKernelGGL(sparse_conv_mfma, dim3(NB2), dim3(256), 0,
                       stream, xt, index, itp, wbf, bias, out);
}